// Round 1
// baseline (43.172 us; speedup 1.0000x reference)
//
#include <hip/hip_runtime.h>

// PS-ROI pooling, matches jax reference exactly in f32.
// inputs: [B=8, H=64, W=64, C=2304] f32 ; boxes: [B, N=128, 4] f32
// out: [B, N, 1, 1, S=256] f32
// One block per (b,n); thread s owns channel s. 81 bilinear samples,
// bin (by,bx) reads channel group tb*S + s.

#define BATCH 8
#define NBOX  128
#define IH    64
#define IW    64
#define IC    2304
#define SCH   256   // IC / 9

__global__ __launch_bounds__(256) void psroi_kernel(
    const float* __restrict__ inp,
    const float* __restrict__ boxes,
    float* __restrict__ out)
{
    const int blk = blockIdx.x;       // b*NBOX + n
    const int b   = blk >> 7;
    const int s   = threadIdx.x;      // 0..255 channel within group

    const float* bp = boxes + (size_t)blk * 4;
    const float y1 = bp[0];
    const float x1 = bp[1];
    const float y2 = bp[2];
    const float x2 = bp[3];

    const float sy = (y2 - y1) * (1.0f / 3.0f);
    const float sx = (x2 - x1) * (1.0f / 3.0f);

    // Separable sample coordinates: jy = by*3 + i  (9 each axis).
    int   y0i[9], y1i[9], x0i[9], x1i[9];
    float ly[9], lx[9];
    bool  vy[9], vx[9];

    #pragma unroll
    for (int by = 0; by < 3; ++by) {
        #pragma unroll
        for (int i = 0; i < 3; ++i) {
            const int j = by * 3 + i;
            // ys = (y1 + by*sy)*(H-1) + i*sy*(H-1)/(CROP-1)
            float ys = (y1 + (float)by * sy) * 63.0f + (float)i * sy * 63.0f * 0.5f;
            float xs = (x1 + (float)by * sx) * 63.0f + (float)i * sx * 63.0f * 0.5f;
            vy[j] = (ys >= 0.0f) && (ys <= 63.0f);
            vx[j] = (xs >= 0.0f) && (xs <= 63.0f);
            float ysc = fminf(fmaxf(ys, 0.0f), 63.0f);
            float xsc = fminf(fmaxf(xs, 0.0f), 63.0f);
            float yf = floorf(ysc);
            float xf = floorf(xsc);
            ly[j] = ysc - yf;
            lx[j] = xsc - xf;
            int yi = (int)yf;
            int xi = (int)xf;
            y0i[j] = yi;
            y1i[j] = (yi + 1 < 63) ? (yi + 1) : 63;
            x0i[j] = xi;
            x1i[j] = (xi + 1 < 63) ? (xi + 1) : 63;
        }
    }

    const float* base = inp + (size_t)b * (IH * IW * IC) + s;

    float acc = 0.0f;

    #pragma unroll
    for (int by = 0; by < 3; ++by) {
        #pragma unroll
        for (int bx = 0; bx < 3; ++bx) {
            const int tb = by * 3 + bx;
            const float* gbase = base + tb * SCH;
            #pragma unroll
            for (int cy = 0; cy < 3; ++cy) {
                const int jy = by * 3 + cy;
                const int r0 = y0i[jy] * IW;
                const int r1 = y1i[jy] * IW;
                const float wy = ly[jy];
                #pragma unroll
                for (int cx = 0; cx < 3; ++cx) {
                    const int jx = bx * 3 + cx;
                    if (vy[jy] && vx[jx]) {
                        const int c0 = x0i[jx];
                        const int c1 = x1i[jx];
                        const float wx = lx[jx];
                        const float a  = gbase[(size_t)(r0 + c0) * IC];
                        const float bb = gbase[(size_t)(r0 + c1) * IC];
                        const float cc = gbase[(size_t)(r1 + c0) * IC];
                        const float dd = gbase[(size_t)(r1 + c1) * IC];
                        const float top = a  * (1.0f - wx) + bb * wx;
                        const float bot = cc * (1.0f - wx) + dd * wx;
                        acc += top * (1.0f - wy) + bot * wy;
                    }
                }
            }
        }
    }

    out[(size_t)blk * SCH + s] = acc * (1.0f / 81.0f);
}

extern "C" void kernel_launch(void* const* d_in, const int* in_sizes, int n_in,
                              void* d_out, int out_size, void* d_ws, size_t ws_size,
                              hipStream_t stream) {
    const float* inp   = (const float*)d_in[0];
    const float* boxes = (const float*)d_in[1];
    float* out = (float*)d_out;

    dim3 grid(BATCH * NBOX);
    dim3 block(256);
    psroi_kernel<<<grid, block, 0, stream>>>(inp, boxes, out);
}

// Round 2
// 42.493 us; speedup vs baseline: 1.0160x; 1.0160x over previous
//
#include <hip/hip_runtime.h>

// PS-ROI pooling. inputs: [8,64,64,2304] f32 ; boxes: [8,128,4] f32
// out: [8,128,1,1,256] f32
// One 64-thread block (1 wave) per box; thread lane owns channels 4*lane..4*lane+3
// via float4 gathers (16B/lane x 64 lanes = full 1KB channel-group per instr).
// blockIdx % 8 = image index -> all blocks of an image land on one XCD
// (dispatch round-robins XCDs), improving per-XCD L2 reuse.

#define BATCH 8
#define NBOX  128
#define IH    64
#define IW    64
#define IC    2304
#define SCH   256   // IC / 9

typedef float f32x4 __attribute__((ext_vector_type(4)));

__global__ __launch_bounds__(64) void psroi_kernel(
    const float* __restrict__ inp,
    const float* __restrict__ boxes,
    float* __restrict__ out)
{
    const int blk  = blockIdx.x;
    const int b    = blk & 7;      // image  (XCD-aligned)
    const int n    = blk >> 3;     // box within image
    const int box  = b * NBOX + n;
    const int lane = threadIdx.x;  // 0..63

    const float* bp = boxes + (size_t)box * 4;
    const float y1 = bp[0];
    const float x1 = bp[1];
    const float y2 = bp[2];
    const float x2 = bp[3];

    const float sy = (y2 - y1) * (1.0f / 3.0f);
    const float sx = (x2 - x1) * (1.0f / 3.0f);

    // Separable sample coordinates: jy = by*3 + i  (9 each axis).
    int   y0i[9], y1i[9], x0i[9], x1i[9];
    float ly[9], lx[9];
    bool  vy[9], vx[9];

    #pragma unroll
    for (int by = 0; by < 3; ++by) {
        #pragma unroll
        for (int i = 0; i < 3; ++i) {
            const int j = by * 3 + i;
            float ys = (y1 + (float)by * sy) * 63.0f + (float)i * sy * 63.0f * 0.5f;
            float xs = (x1 + (float)by * sx) * 63.0f + (float)i * sx * 63.0f * 0.5f;
            vy[j] = (ys >= 0.0f) && (ys <= 63.0f);
            vx[j] = (xs >= 0.0f) && (xs <= 63.0f);
            float ysc = fminf(fmaxf(ys, 0.0f), 63.0f);
            float xsc = fminf(fmaxf(xs, 0.0f), 63.0f);
            float yf = floorf(ysc);
            float xf = floorf(xsc);
            ly[j] = ysc - yf;
            lx[j] = xsc - xf;
            int yi = (int)yf;
            int xi = (int)xf;
            y0i[j] = yi;
            y1i[j] = (yi + 1 < 63) ? (yi + 1) : 63;
            x0i[j] = xi;
            x1i[j] = (xi + 1 < 63) ? (xi + 1) : 63;
        }
    }

    // Per-lane base: image b, channel 4*lane within the bin's channel group.
    const float* base = inp + (size_t)b * (IH * IW * IC) + lane * 4;

    f32x4 acc = {0.0f, 0.0f, 0.0f, 0.0f};

    #pragma unroll
    for (int by = 0; by < 3; ++by) {
        #pragma unroll
        for (int bx = 0; bx < 3; ++bx) {
            const int tb = by * 3 + bx;
            const float* gbase = base + tb * SCH;
            #pragma unroll
            for (int cy = 0; cy < 3; ++cy) {
                const int jy = by * 3 + cy;
                const int r0 = y0i[jy] * IW;
                const int r1 = y1i[jy] * IW;
                const float wy = ly[jy];
                #pragma unroll
                for (int cx = 0; cx < 3; ++cx) {
                    const int jx = bx * 3 + cx;
                    if (vy[jy] && vx[jx]) {
                        const int c0 = x0i[jx];
                        const int c1 = x1i[jx];
                        const float wx = lx[jx];
                        const f32x4 a  = *reinterpret_cast<const f32x4*>(gbase + (size_t)(r0 + c0) * IC);
                        const f32x4 bb = *reinterpret_cast<const f32x4*>(gbase + (size_t)(r0 + c1) * IC);
                        const f32x4 cc = *reinterpret_cast<const f32x4*>(gbase + (size_t)(r1 + c0) * IC);
                        const f32x4 dd = *reinterpret_cast<const f32x4*>(gbase + (size_t)(r1 + c1) * IC);
                        const f32x4 top = a  * (1.0f - wx) + bb * wx;
                        const f32x4 bot = cc * (1.0f - wx) + dd * wx;
                        acc += top * (1.0f - wy) + bot * wy;
                    }
                }
            }
        }
    }

    acc *= (1.0f / 81.0f);
    *reinterpret_cast<f32x4*>(out + (size_t)box * SCH + lane * 4) = acc;
}

extern "C" void kernel_launch(void* const* d_in, const int* in_sizes, int n_in,
                              void* d_out, int out_size, void* d_ws, size_t ws_size,
                              hipStream_t stream) {
    const float* inp   = (const float*)d_in[0];
    const float* boxes = (const float*)d_in[1];
    float* out = (float*)d_out;

    dim3 grid(BATCH * NBOX);
    dim3 block(64);
    psroi_kernel<<<grid, block, 0, stream>>>(inp, boxes, out);
}

// Round 3
// 28.339 us; speedup vs baseline: 1.5234x; 1.4994x over previous
//
#include <hip/hip_runtime.h>

// PS-ROI pooling. inputs: [8,64,64,2304] f32 ; boxes: [8,128,4] f32
// out: [8,128,1,1,256] f32
// One 256-thread block (4 waves) per box. Each wave covers all 256 channels
// (4 per lane via float4 gathers) and a quarter of the 81 sample points
// (p & 3 == wave). Partial sums reduced via LDS.
// blockIdx % 8 = image index -> all blocks of an image land on one XCD.

#define BATCH 8
#define NBOX  128
#define IH    64
#define IW    64
#define IC    2304
#define SCH   256   // IC / 9

typedef float f32x4 __attribute__((ext_vector_type(4)));

__global__ __launch_bounds__(256) void psroi_kernel(
    const float* __restrict__ inp,
    const float* __restrict__ boxes,
    float* __restrict__ out)
{
    const int blk  = blockIdx.x;
    const int b    = blk & 7;      // image  (XCD-aligned)
    const int n    = blk >> 3;     // box within image
    const int box  = b * NBOX + n;
    const int tid  = threadIdx.x;
    const int lane = tid & 63;     // 0..63  -> channels 4*lane..4*lane+3
    const int w    = tid >> 6;     // wave 0..3 -> sample subset

    const float* bp = boxes + (size_t)box * 4;
    const float y1 = bp[0];
    const float x1 = bp[1];
    const float y2 = bp[2];
    const float x2 = bp[3];

    const float sy = (y2 - y1) * (1.0f / 3.0f);
    const float sx = (x2 - x1) * (1.0f / 3.0f);

    // Separable sample coordinates: jy = by*3 + i  (9 each axis).
    int   y0i[9], y1i[9], x0i[9], x1i[9];
    float ly[9], lx[9];
    bool  vy[9], vx[9];

    #pragma unroll
    for (int by = 0; by < 3; ++by) {
        #pragma unroll
        for (int i = 0; i < 3; ++i) {
            const int j = by * 3 + i;
            float ys = (y1 + (float)by * sy) * 63.0f + (float)i * sy * 63.0f * 0.5f;
            float xs = (x1 + (float)by * sx) * 63.0f + (float)i * sx * 63.0f * 0.5f;
            vy[j] = (ys >= 0.0f) && (ys <= 63.0f);
            vx[j] = (xs >= 0.0f) && (xs <= 63.0f);
            float ysc = fminf(fmaxf(ys, 0.0f), 63.0f);
            float xsc = fminf(fmaxf(xs, 0.0f), 63.0f);
            float yf = floorf(ysc);
            float xf = floorf(xsc);
            ly[j] = ysc - yf;
            lx[j] = xsc - xf;
            int yi = (int)yf;
            int xi = (int)xf;
            y0i[j] = yi;
            y1i[j] = (yi + 1 < 63) ? (yi + 1) : 63;
            x0i[j] = xi;
            x1i[j] = (xi + 1 < 63) ? (xi + 1) : 63;
        }
    }

    // Per-lane base: image b, channel 4*lane within the bin's channel group.
    const float* base = inp + (size_t)b * (IH * IW * IC) + lane * 4;

    f32x4 acc = {0.0f, 0.0f, 0.0f, 0.0f};

    #pragma unroll
    for (int by = 0; by < 3; ++by) {
        #pragma unroll
        for (int bx = 0; bx < 3; ++bx) {
            const int tb = by * 3 + bx;
            const float* gbase = base + tb * SCH;
            #pragma unroll
            for (int cy = 0; cy < 3; ++cy) {
                const int jy = by * 3 + cy;
                const int r0 = y0i[jy] * IW;
                const int r1 = y1i[jy] * IW;
                const float wy = ly[jy];
                #pragma unroll
                for (int cx = 0; cx < 3; ++cx) {
                    const int p = ((by * 3 + bx) * 3 + cy) * 3 + cx;
                    if ((p & 3) != w) continue;   // wave-uniform guard
                    const int jx = bx * 3 + cx;
                    if (vy[jy] && vx[jx]) {
                        const int c0 = x0i[jx];
                        const int c1 = x1i[jx];
                        const float wx = lx[jx];
                        const f32x4 a  = *reinterpret_cast<const f32x4*>(gbase + (size_t)(r0 + c0) * IC);
                        const f32x4 bb = *reinterpret_cast<const f32x4*>(gbase + (size_t)(r0 + c1) * IC);
                        const f32x4 cc = *reinterpret_cast<const f32x4*>(gbase + (size_t)(r1 + c0) * IC);
                        const f32x4 dd = *reinterpret_cast<const f32x4*>(gbase + (size_t)(r1 + c1) * IC);
                        const f32x4 top = a  * (1.0f - wx) + bb * wx;
                        const f32x4 bot = cc * (1.0f - wx) + dd * wx;
                        acc += top * (1.0f - wy) + bot * wy;
                    }
                }
            }
        }
    }

    // Reduce 4 waves' partial sums via LDS.
    __shared__ float red[4][SCH];
    *reinterpret_cast<f32x4*>(&red[w][lane * 4]) = acc;
    __syncthreads();

    const float v = (red[0][tid] + red[1][tid]) + (red[2][tid] + red[3][tid]);
    out[(size_t)box * SCH + tid] = v * (1.0f / 81.0f);
}

extern "C" void kernel_launch(void* const* d_in, const int* in_sizes, int n_in,
                              void* d_out, int out_size, void* d_ws, size_t ws_size,
                              hipStream_t stream) {
    const float* inp   = (const float*)d_in[0];
    const float* boxes = (const float*)d_in[1];
    float* out = (float*)d_out;

    dim3 grid(BATCH * NBOX);
    dim3 block(256);
    psroi_kernel<<<grid, block, 0, stream>>>(inp, boxes, out);
}